// Round 19
// baseline (335.294 us; speedup 1.0000x reference)
//
#include <hip/hip_runtime.h>

#define VOCAB 50257
#define NB 512
#define NT 2048
#define NOUT 128
#define CHUNK 32

#define QP_XOR1 0xB1   // quad_perm [1,0,3,2]
#define QP_PAIR 0xA0   // quad_perm [0,0,2,2]
#define QP_CROSS 0x0A  // quad_perm [2,2,0,0]

template<int CTRL>
__device__ __forceinline__ float qp(float v){
    return __int_as_float(__builtin_amdgcn_update_dpp(0, __float_as_int(v), CTRL, 0xF, 0xF, true));
}

// All nonlinearities via clamped Pade[5/5] tanh:
//   tanh(z) ~ z(945+105z^2+z^4)/(945+420z^2+15z^4),  z clamped to [-4,4]
//   sigma(x) = 0.5 + 0.5*tanh(x/2)  (the 1/2 folded into weights/table)
// Gate rows perm p={i0,f0,g0,o0,i1,f1,g1,o1}; scale 0.5 for i/f/o rows, 1.0 for g.

// K1: tab[v][p] = s(p) * (b0[rj] + emb[v]·Wih0[rj])
__global__ __launch_bounds__(256) void build_table(const float* __restrict__ emb,
                                                   const float* __restrict__ Wih0,
                                                   const float* __restrict__ b0,
                                                   float* __restrict__ tab){
    int v = blockIdx.x*256 + threadIdx.x;
    if (v >= VOCAB) return;
    const float4* ep = (const float4*)(emb + (size_t)v*8);
    float4 e0 = ep[0], e1 = ep[1];
    float e[8] = {e0.x,e0.y,e0.z,e0.w,e1.x,e1.y,e1.z,e1.w};
    const int perm[8] = {0,2,4,6,1,3,5,7};
    float o[8];
#pragma unroll
    for (int p=0;p<8;p++){
        int rj = perm[p];
        float s = b0[rj];
#pragma unroll
        for (int d=0;d<8;d++) s = fmaf(e[d], Wih0[rj*8+d], s);
        o[p] = s * ((rj==4||rj==5) ? 1.0f : 0.5f);
    }
    float4* tp = (float4*)(tab + (size_t)v*8);
    tp[0] = make_float4(o[0],o[1],o[2],o[3]);
    tp[1] = make_float4(o[4],o[5],o[6],o[7]);
}

// K1b: gx[t][b][0..7] = tab[x[b][t]][0..7] — parallel gather on all CUs.
__global__ __launch_bounds__(256) void expand_gates(const int* __restrict__ x,
                                                    const float* __restrict__ tab,
                                                    float4* __restrict__ gx){
    int gid = blockIdx.x*256 + threadIdx.x;   // [0, B*T)
    int t = gid >> 9;
    int b = gid & (NB-1);
    int tok = x[(size_t)b*NT + t];
    const float4* tp = (const float4*)tab + (size_t)tok*2;
    float4 v0 = tp[0], v1 = tp[1];
    gx[(size_t)gid*2]   = v0;
    gx[(size_t)gid*2+1] = v1;
}

__device__ __forceinline__ float tanh_pade(float z){
    z = fminf(fmaxf(z, -4.0f), 4.0f);         // v_med3 clamp
    float z2 = z*z;
    float nq = fmaf(z2, z2 + 105.0f, 945.0f);
    float dq = fmaf(z2, fmaf(15.0f, z2, 420.0f), 945.0f);
    return z*nq*__builtin_amdgcn_rcpf(dq);
}

// Uniform gate nonlinearity + quad combine — ZERO exp2 on the chain.
// v0: l&1 ? tanh(g) : sigma(i);  v1: sigma(f or o) = 0.5+0.5*tanh.
#define GATE_COMBINE(x0, x1, CC, HS, HO) { \
    float tp0 = tanh_pade(x0); \
    float tp1 = tanh_pade(x1); \
    float v0 = fmaf(B0, tp0, A0); \
    float v1 = fmaf(0.5f, tp1, 0.5f); \
    float u0 = qp<QP_XOR1>(v0); \
    float u1 = qp<QP_XOR1>(v1); \
    CC = fmaf(v1, CC, v0*u0); \
    float th = tanh_pade(CC); \
    float hh = u1*th; \
    HS = qp<QP_PAIR>(hh); \
    HO = qp<QP_CROSS>(hh); }

// K2: layer-pipelined scan, 4 lanes/row. Block = 128 thr = 2 waves;
// wave0 = layer0 (gx -> LDS h0 chunks), wave1 = layer1 (LDS -> y1).
__global__ __launch_bounds__(128) void lstm_pipe(const float2* __restrict__ gx,
                                                 const float* __restrict__ Whh0,
                                                 const float* __restrict__ Wih1,
                                                 const float* __restrict__ Whh1,
                                                 const float* __restrict__ b1,
                                                 float* __restrict__ y1out,   // [T][B][2]
                                                 float* __restrict__ tail){
    __shared__ float h0buf[2][CHUNK][16][2];   // 8 KB double buffer
    const int tid  = threadIdx.x;
    const int wv   = tid >> 6;
    const int lane = tid & 63;
    const int l    = lane & 3;
    const int lrow = lane >> 2;               // 0..15
    const int row  = blockIdx.x*16 + lrow;
    const int e    = l >> 1;                  // element this pair serves
    const int rj0  = (l&1)*4 + e;             // gate row of value 0 (i or g)
    const int rj1  = rj0 + 2;                 // gate row of value 1 (f or o)
    const float s0 = (l&1) ? 1.0f : 0.5f;     // tanh row natural, sigma row half
    const float s1 = 0.5f;
    const float A0 = (l&1) ? 0.0f : 0.5f;
    const float B0 = (l&1) ? 1.0f : 0.5f;

    // wave0 weights (layer 0)
    const float wS0 = Whh0[rj0*2+e]*s0,  wO0 = Whh0[rj0*2+(e^1)]*s0;
    const float wS1 = Whh0[rj1*2+e]*s1,  wO1 = Whh0[rj1*2+(e^1)]*s1;
    // wave1 weights (layer 1)
    const float wi00 = Wih1[rj0*2+0]*s0, wi01 = Wih1[rj0*2+1]*s0;
    const float wi10 = Wih1[rj1*2+0]*s1, wi11 = Wih1[rj1*2+1]*s1;
    const float whS0 = Whh1[rj0*2+e]*s0, whO0 = Whh1[rj0*2+(e^1)]*s0;
    const float whS1 = Whh1[rj1*2+e]*s1, whO1 = Whh1[rj1*2+(e^1)]*s1;
    const float bb0  = b1[rj0]*s0,       bb1  = b1[rj1]*s1;

    float hs=0.f, ho=0.f, c=0.f;
    const size_t ST = (size_t)NB*4;           // float2 stride per t
    const float2* __restrict__ gp = gx + (size_t)row*4 + l;
    float2 f0,f1,f2,f3,f4,f5,f6,f7;
    if (wv==0){
        f0=gp[0*ST]; f1=gp[1*ST]; f2=gp[2*ST]; f3=gp[3*ST];
        f4=gp[4*ST]; f5=gp[5*ST]; f6=gp[6*ST]; f7=gp[7*ST];
    }

    for (int cidx=0; cidx<=NT/CHUNK; ++cidx){
        if (wv==0){
            if (cidx < NT/CHUNK){
                const int buf = cidx & 1;
                const int base = cidx*CHUNK;
#define PSTEP(F, SS) { \
    float2 nf = gp[(size_t)(base+(SS)+8)*ST]; /* <= gx[NT+7]: in-bounds d_out scratch, values unused */ \
    float x0 = fmaf(wS0,hs, fmaf(wO0,ho, F.x)); \
    float x1 = fmaf(wS1,hs, fmaf(wO1,ho, F.y)); \
    GATE_COMBINE(x0, x1, c, hs, ho) \
    h0buf[buf][SS][lrow][e] = hs; \
    F = nf; }
                for (int s=0; s<CHUNK; s+=8){
                    PSTEP(f0,s+0) PSTEP(f1,s+1) PSTEP(f2,s+2) PSTEP(f3,s+3)
                    PSTEP(f4,s+4) PSTEP(f5,s+5) PSTEP(f6,s+6) PSTEP(f7,s+7)
                }
#undef PSTEP
            }
        } else {
            if (cidx >= 1){
                const int buf = (cidx-1) & 1;
                const int base = (cidx-1)*CHUNK;
#pragma unroll 8
                for (int s=0; s<CHUNK; ++s){
                    const float2 h0v = *(const float2*)&h0buf[buf][s][lrow][0];
                    float x0 = fmaf(whS0,hs, fmaf(whO0,ho, fmaf(wi00,h0v.x, fmaf(wi01,h0v.y, bb0))));
                    float x1 = fmaf(whS1,hs, fmaf(whO1,ho, fmaf(wi10,h0v.x, fmaf(wi11,h0v.y, bb1))));
                    GATE_COMBINE(x0, x1, c, hs, ho)
                    y1out[((size_t)(base+s)*NB + row)*2 + e] = hs;
                }
            }
        }
        __syncthreads();
    }
    const float cs = qp<QP_PAIR>(c);          // valid c lives on lanes 0,2
    if (wv==0){
        tail[row*2+e]          = hs;   // h_n[0]
        tail[2*NB*2 + row*2+e] = cs;   // c_n[0]
    } else {
        tail[NB*2 + row*2+e]   = hs;   // h_n[1]
        tail[3*NB*2 + row*2+e] = cs;   // c_n[1]
    }
}

// K3: out[bt][j] = y1[bt]·Wfc[j] + bfc[j]; one float4 store per thread.
__global__ __launch_bounds__(256) void fc_out(const float* __restrict__ y1,
                                              const float* __restrict__ Wfc,
                                              const float* __restrict__ bfc,
                                              float* __restrict__ out){
    const int tid = threadIdx.x;
    const int j4  = tid & 31;
    const int btl = tid >> 5;
    const int bt  = blockIdx.x*8 + btl;
    const int b   = bt >> 11;
    const int tt  = bt & (NT-1);
    const float2 y  = *(const float2*)(y1 + ((size_t)tt*NB + b)*2);
    const float4 wa = *(const float4*)(Wfc + j4*8);
    const float4 wb = *(const float4*)(Wfc + j4*8+4);
    const float4 bbv= *(const float4*)(bfc + j4*4);
    float4 o;
    o.x = fmaf(y.x,wa.x, fmaf(y.y,wa.y, bbv.x));
    o.y = fmaf(y.x,wa.z, fmaf(y.y,wa.w, bbv.y));
    o.z = fmaf(y.x,wb.x, fmaf(y.y,wb.y, bbv.z));
    o.w = fmaf(y.x,wb.z, fmaf(y.y,wb.w, bbv.w));
    *(float4*)(out + (size_t)bt*128 + j4*4) = o;
}

extern "C" void kernel_launch(void* const* d_in, const int* in_sizes, int n_in,
                              void* d_out, int out_size, void* d_ws, size_t ws_size,
                              hipStream_t stream){
    const int*   x    = (const int*)d_in[0];
    const float* emb  = (const float*)d_in[1];
    const float* Wih0 = (const float*)d_in[2];
    const float* Whh0 = (const float*)d_in[3];
    const float* b0   = (const float*)d_in[4];
    const float* Wih1 = (const float*)d_in[5];
    const float* Whh1 = (const float*)d_in[6];
    const float* b1   = (const float*)d_in[7];
    const float* Wfc  = (const float*)d_in[8];
    const float* bfc  = (const float*)d_in[9];
    float* out  = (float*)d_out;
    float* tab  = (float*)d_ws;                       // VOCAB*8 floats = 1.6 MB (ws)
    float* y1   = tab + (size_t)VOCAB*8;              // T*B*2 floats = 8 MB (ws)
    float* tail = out + (size_t)NB*NT*NOUT;           // h_n|c_n region of d_out
    float4* gxs = (float4*)d_out;                     // 33.6 MB scratch in d_out; dead before fc_out writes

    build_table<<<(VOCAB+255)/256, 256, 0, stream>>>(emb, Wih0, b0, tab);
    expand_gates<<<(NB*NT)/256, 256, 0, stream>>>(x, tab, gxs);
    lstm_pipe<<<32, 128, 0, stream>>>((const float2*)gxs, Whh0, Wih1, Whh1, b1, y1, tail);
    fc_out<<<(NB*NT)/8, 256, 0, stream>>>(y1, Wfc, bfc, out);
}

// Round 20
// 291.726 us; speedup vs baseline: 1.1493x; 1.1493x over previous
//
#include <hip/hip_runtime.h>

#define VOCAB 50257
#define NB 512
#define NT 2048
#define NOUT 128
#define CHUNK 32
#define L2E 1.4426950408889634f

#define QP_XOR1 0xB1   // quad_perm [1,0,3,2]
#define QP_PAIR 0xA0   // quad_perm [0,0,2,2]
#define QP_CROSS 0x0A  // quad_perm [2,2,0,0]

template<int CTRL>
__device__ __forceinline__ float qp(float v){
    return __int_as_float(__builtin_amdgcn_update_dpp(0, __float_as_int(v), CTRL, 0xF, 0xF, true));
}

// K1: tab[v][p], p=0..7 -> gate rows perm={i0,f0,g0,o0,i1,f1,g1,o1} with folded
// scale: -log2e for sigmoid rows (i,f,o), +2log2e for tanh rows (g).
__global__ __launch_bounds__(256) void build_table(const float* __restrict__ emb,
                                                   const float* __restrict__ Wih0,
                                                   const float* __restrict__ b0,
                                                   float* __restrict__ tab){
    int v = blockIdx.x*256 + threadIdx.x;
    if (v >= VOCAB) return;
    const float4* ep = (const float4*)(emb + (size_t)v*8);
    float4 e0 = ep[0], e1 = ep[1];
    float e[8] = {e0.x,e0.y,e0.z,e0.w,e1.x,e1.y,e1.z,e1.w};
    const int perm[8] = {0,2,4,6,1,3,5,7};
    float o[8];
#pragma unroll
    for (int p=0;p<8;p++){
        int rj = perm[p];
        float s = b0[rj];
#pragma unroll
        for (int d=0;d<8;d++) s = fmaf(e[d], Wih0[rj*8+d], s);
        o[p] = s * ((rj==4||rj==5) ? 2.0f*L2E : -L2E);
    }
    float4* tp = (float4*)(tab + (size_t)v*8);
    tp[0] = make_float4(o[0],o[1],o[2],o[3]);
    tp[1] = make_float4(o[4],o[5],o[6],o[7]);
}

// K1b: gx[t][b][0..7] = tab[x[b][t]][0..7] — parallel gather on all CUs.
__global__ __launch_bounds__(256) void expand_gates(const int* __restrict__ x,
                                                    const float* __restrict__ tab,
                                                    float4* __restrict__ gx){
    int gid = blockIdx.x*256 + threadIdx.x;   // [0, B*T)
    int t = gid >> 9;
    int b = gid & (NB-1);
    int tok = x[(size_t)b*NT + t];
    const float4* tp = (const float4*)tab + (size_t)tok*2;
    float4 v0 = tp[0], v1 = tp[1];
    gx[(size_t)gid*2]   = v0;
    gx[(size_t)gid*2+1] = v1;
}

// Uniform gate nonlinearity + quad combine. c natural; tanh(c) via Pade[5/5]
// (division-free except one rcp): tanh(c) = c(945+105c^2+c^4)/(945+420c^2+15c^4).
#define GATE_COMBINE(x0, x1, CC, HS, HO) { \
    float ex0 = __builtin_amdgcn_exp2f(x0); \
    float ex1 = __builtin_amdgcn_exp2f(x1); \
    float r0 = __builtin_amdgcn_rcpf(1.0f+ex0); \
    float r1 = __builtin_amdgcn_rcpf(1.0f+ex1); \
    float v0 = fmaf(B0, r0, A0); \
    float u0 = qp<QP_XOR1>(v0); \
    float u1 = qp<QP_XOR1>(r1); \
    CC = fmaf(r1, CC, v0*u0); \
    float t2 = CC*CC; \
    float nq = fmaf(t2, t2 + 105.0f, 945.0f); \
    float dq = fmaf(t2, fmaf(15.0f, t2, 420.0f), 945.0f); \
    float th = CC*nq*__builtin_amdgcn_rcpf(dq); \
    float hh = u1*th; \
    HS = qp<QP_PAIR>(hh); \
    HO = qp<QP_CROSS>(hh); }

// K2: layer-pipelined scan, 4 lanes/row. Block = 128 thr = 2 waves;
// wave0 = layer0 (gx -> LDS h0 chunks), wave1 = layer1 (LDS -> y1).
__global__ __launch_bounds__(128) void lstm_pipe(const float2* __restrict__ gx,
                                                 const float* __restrict__ Whh0,
                                                 const float* __restrict__ Wih1,
                                                 const float* __restrict__ Whh1,
                                                 const float* __restrict__ b1,
                                                 float* __restrict__ y1out,   // [T][B][2]
                                                 float* __restrict__ tail){
    __shared__ float h0buf[2][CHUNK][16][2];   // 8 KB double buffer
    const int tid  = threadIdx.x;
    const int wv   = tid >> 6;
    const int lane = tid & 63;
    const int l    = lane & 3;
    const int lrow = lane >> 2;               // 0..15
    const int row  = blockIdx.x*16 + lrow;
    const int e    = l >> 1;                  // element this pair serves
    const int rj0  = (l&1)*4 + e;             // gate row of value 0 (i or g)
    const int rj1  = rj0 + 2;                 // gate row of value 1 (f or o)
    const float s0 = (l&1) ? 2.0f*L2E : -L2E;
    const float s1 = -L2E;
    const float A0 = (l&1) ? 1.0f : 0.0f;
    const float B0 = (l&1) ? -2.0f : 1.0f;

    // wave0 weights (layer 0)
    const float wS0 = Whh0[rj0*2+e]*s0,  wO0 = Whh0[rj0*2+(e^1)]*s0;
    const float wS1 = Whh0[rj1*2+e]*s1,  wO1 = Whh0[rj1*2+(e^1)]*s1;
    // wave1 weights (layer 1)
    const float wi00 = Wih1[rj0*2+0]*s0, wi01 = Wih1[rj0*2+1]*s0;
    const float wi10 = Wih1[rj1*2+0]*s1, wi11 = Wih1[rj1*2+1]*s1;
    const float whS0 = Whh1[rj0*2+e]*s0, whO0 = Whh1[rj0*2+(e^1)]*s0;
    const float whS1 = Whh1[rj1*2+e]*s1, whO1 = Whh1[rj1*2+(e^1)]*s1;
    const float bb0  = b1[rj0]*s0,       bb1  = b1[rj1]*s1;

    float hs=0.f, ho=0.f, c=0.f;
    const size_t ST = (size_t)NB*4;           // float2 stride per t
    const float2* __restrict__ gp = gx + (size_t)row*4 + l;
    float2 f0,f1,f2,f3,f4,f5,f6,f7;
    if (wv==0){
        f0=gp[0*ST]; f1=gp[1*ST]; f2=gp[2*ST]; f3=gp[3*ST];
        f4=gp[4*ST]; f5=gp[5*ST]; f6=gp[6*ST]; f7=gp[7*ST];
    }

    for (int cidx=0; cidx<=NT/CHUNK; ++cidx){
        if (wv==0){
            if (cidx < NT/CHUNK){
                const int buf = cidx & 1;
                const int base = cidx*CHUNK;
#define PSTEP(F, SS) { \
    float2 nf = gp[(size_t)(base+(SS)+8)*ST]; /* <= gx[NT+7]: in-bounds scratch, unused values */ \
    float x0 = fmaf(wS0,hs, fmaf(wO0,ho, F.x)); \
    float x1 = fmaf(wS1,hs, fmaf(wO1,ho, F.y)); \
    GATE_COMBINE(x0, x1, c, hs, ho) \
    h0buf[buf][SS][lrow][e] = hs; \
    F = nf; }
                for (int s=0; s<CHUNK; s+=8){
                    PSTEP(f0,s+0) PSTEP(f1,s+1) PSTEP(f2,s+2) PSTEP(f3,s+3)
                    PSTEP(f4,s+4) PSTEP(f5,s+5) PSTEP(f6,s+6) PSTEP(f7,s+7)
                }
#undef PSTEP
            }
        } else {
            if (cidx >= 1){
                const int buf = (cidx-1) & 1;
                const int base = (cidx-1)*CHUNK;
#pragma unroll 8
                for (int s=0; s<CHUNK; ++s){
                    const float2 h0v = *(const float2*)&h0buf[buf][s][lrow][0];
                    float x0 = fmaf(whS0,hs, fmaf(whO0,ho, fmaf(wi00,h0v.x, fmaf(wi01,h0v.y, bb0))));
                    float x1 = fmaf(whS1,hs, fmaf(whO1,ho, fmaf(wi10,h0v.x, fmaf(wi11,h0v.y, bb1))));
                    GATE_COMBINE(x0, x1, c, hs, ho)
                    y1out[((size_t)(base+s)*NB + row)*2 + e] = hs;
                }
            }
        }
        __syncthreads();
    }
    const float cs = qp<QP_PAIR>(c);          // valid c lives on lanes 0,2
    if (wv==0){
        tail[row*2+e]          = hs;   // h_n[0]
        tail[2*NB*2 + row*2+e] = cs;   // c_n[0]
    } else {
        tail[NB*2 + row*2+e]   = hs;   // h_n[1]
        tail[3*NB*2 + row*2+e] = cs;   // c_n[1]
    }
}

// K3: out[bt][j] = y1[bt]·Wfc[j] + bfc[j]; one float4 store per thread.
__global__ __launch_bounds__(256) void fc_out(const float* __restrict__ y1,
                                              const float* __restrict__ Wfc,
                                              const float* __restrict__ bfc,
                                              float* __restrict__ out){
    const int tid = threadIdx.x;
    const int j4  = tid & 31;
    const int btl = tid >> 5;
    const int bt  = blockIdx.x*8 + btl;
    const int b   = bt >> 11;
    const int tt  = bt & (NT-1);
    const float2 y  = *(const float2*)(y1 + ((size_t)tt*NB + b)*2);
    const float4 wa = *(const float4*)(Wfc + j4*8);
    const float4 wb = *(const float4*)(Wfc + j4*8+4);
    const float4 bbv= *(const float4*)(bfc + j4*4);
    float4 o;
    o.x = fmaf(y.x,wa.x, fmaf(y.y,wa.y, bbv.x));
    o.y = fmaf(y.x,wa.z, fmaf(y.y,wa.w, bbv.y));
    o.z = fmaf(y.x,wb.x, fmaf(y.y,wb.y, bbv.z));
    o.w = fmaf(y.x,wb.z, fmaf(y.y,wb.w, bbv.w));
    *(float4*)(out + (size_t)bt*128 + j4*4) = o;
}

extern "C" void kernel_launch(void* const* d_in, const int* in_sizes, int n_in,
                              void* d_out, int out_size, void* d_ws, size_t ws_size,
                              hipStream_t stream){
    const int*   x    = (const int*)d_in[0];
    const float* emb  = (const float*)d_in[1];
    const float* Wih0 = (const float*)d_in[2];
    const float* Whh0 = (const float*)d_in[3];
    const float* b0   = (const float*)d_in[4];
    const float* Wih1 = (const float*)d_in[5];
    const float* Whh1 = (const float*)d_in[6];
    const float* b1   = (const float*)d_in[7];
    const float* Wfc  = (const float*)d_in[8];
    const float* bfc  = (const float*)d_in[9];
    float* out  = (float*)d_out;
    float* tab  = (float*)d_ws;                       // VOCAB*8 floats = 1.6 MB (ws)
    float* y1   = tab + (size_t)VOCAB*8;              // T*B*2 floats = 8 MB (ws)
    float* tail = out + (size_t)NB*NT*NOUT;           // h_n|c_n region of d_out
    float4* gxs = (float4*)d_out;                     // 33.6 MB scratch in d_out; dead before fc_out writes

    build_table<<<(VOCAB+255)/256, 256, 0, stream>>>(emb, Wih0, b0, tab);
    expand_gates<<<(NB*NT)/256, 256, 0, stream>>>(x, tab, gxs);
    lstm_pipe<<<32, 128, 0, stream>>>((const float2*)gxs, Whh0, Wih1, Whh1, b1, y1, tail);
    fc_out<<<(NB*NT)/8, 256, 0, stream>>>(y1, Wfc, bfc, out);
}